// Round 7
// baseline (1964.229 us; speedup 1.0000x reference)
//
#include <hip/hip_runtime.h>
#include <hip/hip_bf16.h>

#define VOCAB  400000
#define EMB    300
#define HIDDEN 128
#define OUT    3
#define SEQ    4096
#define SPB    8     // sequences per block in the xproj kernel
#define CHUNK  64    // xp timesteps staged per LDS buffer
#define NCHUNK (SEQ / CHUNK)

typedef float f32x4 __attribute__((ext_vector_type(4)));

// ---------------------------------------------------------------------------
// Kernel A: xproj[s][i] = b_ih[i] + dot(weights[X[s]], W_ih[i])
// (unchanged — round-4 verified; not in the top-5 dispatch list)
// ---------------------------------------------------------------------------
__global__ __launch_bounds__(128) void xproj_kernel(
    const int* __restrict__ X, const float* __restrict__ weights,
    const float* __restrict__ W_ih, const float* __restrict__ b_ih,
    float* __restrict__ xproj)
{
    __shared__ float emb[SPB][EMB];
    __shared__ int xs[SPB];
    const int tid = threadIdx.x;
    const int s0 = blockIdx.x * SPB;

    if (tid < SPB) xs[tid] = X[s0 + tid];
    __syncthreads();

    {
        const float4* w4 = (const float4*)weights;
        float4* e4 = (float4*)&emb[0][0];
        for (int i = tid; i < SPB * (EMB / 4); i += 128) {
            int s = i / (EMB / 4);
            int r = i - s * (EMB / 4);
            e4[i] = w4[(size_t)xs[s] * (EMB / 4) + r];
        }
    }
    __syncthreads();

    const float4* wrow = (const float4*)(W_ih + tid * EMB);
    float acc[SPB];
    #pragma unroll
    for (int s = 0; s < SPB; ++s) acc[s] = 0.f;

    #pragma unroll 5
    for (int r = 0; r < EMB / 4; ++r) {
        float4 w = wrow[r];
        #pragma unroll
        for (int s = 0; s < SPB; ++s) {
            float4 e = *(const float4*)&emb[s][4 * r];   // uniform broadcast
            acc[s] += w.x * e.x;
            acc[s] += w.y * e.y;
            acc[s] += w.z * e.z;
            acc[s] += w.w * e.w;
        }
    }

    const float b = b_ih[tid];
    #pragma unroll
    for (int s = 0; s < SPB; ++s)
        xproj[(size_t)(s0 + s) * HIDDEN + tid] = acc[s] + b;
}

// ---------------------------------------------------------------------------
// Quad butterfly sum via DPP quad_perm (full-rate VALU, no LDS round-trip).
// ---------------------------------------------------------------------------
__device__ __forceinline__ float quad_reduce_add(float x) {
    int t = __builtin_amdgcn_update_dpp(0, __float_as_int(x), 0xB1, 0xF, 0xF, true);
    x += __int_as_float(t);
    t = __builtin_amdgcn_update_dpp(0, __float_as_int(x), 0x4E, 0xF, 0xF, true);
    x += __int_as_float(t);
    return x;
}

// ---------------------------------------------------------------------------
// Kernel B: sequential Elman scan + fc + log_softmax.
// 1 block x 512 threads (8 waves, 2/SIMD). Thread (o=tid>>2, q=tid&3).
// Round-4 fixes:
//  * W_hh quarter-rows PINNED in VGPRs via "+v" asm (VGPR_Count=28 proved the
//    compiler was re-loading W_hh from global every step).
//  * xp staged through a 2x32KB LDS double buffer in 64-step chunks with a
//    register relay: chunk c+1's global loads are issued at the START of
//    chunk c, so no per-step barrier ever drains an outstanding vmem load.
//    Per-step xp read is a broadcast ds_read (conflict-free).
// Interleaved W_hh column partition (quarter q owns float4 cols {4rr+q}) keeps
// all h-reads conflict-free (round-4: SQ_LDS_BANK_CONFLICT == 0).
// ---------------------------------------------------------------------------
__global__ __launch_bounds__(512, 2) void rnn_scan_kernel(
    const float* __restrict__ xproj, const float* __restrict__ W_hh,
    const float* __restrict__ b_hh, const float* __restrict__ W_fc,
    const float* __restrict__ b_fc, float* __restrict__ out)
{
    __shared__ float h_lds[2][HIDDEN];
    __shared__ float xp_lds[2][CHUNK * HIDDEN];   // 2 x 32 KB
    __shared__ float lg[OUT];

    const int tid = threadIdx.x;
    const int o   = tid >> 2;      // output element 0..127
    const int q   = tid & 3;       // interleave phase

    // W_hh row o, float4 columns {4rr+q}, pinned in VGPRs.
    f32x4 w[8];
    {
        const f32x4* wr = (const f32x4*)(W_hh + o * HIDDEN);
        #pragma unroll
        for (int rr = 0; rr < 8; ++rr) w[rr] = wr[4 * rr + q];
        #pragma unroll
        for (int rr = 0; rr < 8; ++rr) asm volatile("" : "+v"(w[rr]));
    }
    const float bh = b_hh[o];

    // register relay: stg holds chunk (t>>6) at each chunk boundary.
    // One chunk = CHUNK*HIDDEN = 8192 floats = 2048 float4 -> 4 per thread.
    const f32x4* xp_g4 = (const f32x4*)xproj;
    f32x4 stg[4];
    #pragma unroll
    for (int i = 0; i < 4; ++i) stg[i] = xp_g4[i * 512 + tid];   // chunk 0

    if (tid < HIDDEN) h_lds[0][tid] = 0.f;   // h0 = 0 (visible at t=0 barrier)

    int cur = 0;
    for (int t = 0; t < SEQ; ++t) {
        const int tc = t & (CHUNK - 1);
        const int cb = (t >> 6) & 1;
        if (tc == 0) {                        // chunk boundary (wave-uniform)
            const int c = t >> 6;
            f32x4* dst = (f32x4*)&xp_lds[c & 1][0];
            #pragma unroll
            for (int i = 0; i < 4; ++i) dst[i * 512 + tid] = stg[i];
            __syncthreads();                  // chunk (and t=0 h-init) visible
            const int cn = (c + 1 < NCHUNK) ? c + 1 : NCHUNK - 1;
            #pragma unroll
            for (int i = 0; i < 4; ++i)       // in flight for the next 64 steps
                stg[i] = xp_g4[(size_t)cn * (CHUNK * HIDDEN / 4) + i * 512 + tid];
        }

        const float xp = xp_lds[cb][tc * HIDDEN + o];   // broadcast ds_read

        const f32x4* hb = (const f32x4*)&h_lds[cur][0] + q;
        float a0 = 0.f, a1 = 0.f, a2 = 0.f, a3 = 0.f;
        #pragma unroll
        for (int rr = 0; rr < 8; ++rr) {
            f32x4 hv = hb[4 * rr];            // ds_read_b128, conflict-free
            a0 += hv[0] * w[rr][0];
            a1 += hv[1] * w[rr][1];
            a2 += hv[2] * w[rr][2];
            a3 += hv[3] * w[rr][3];
        }
        float acc = (a0 + a1) + (a2 + a3);
        acc = quad_reduce_add(acc);           // all 4 quad lanes get the sum

        float z = acc + xp + bh;
        z = fminf(fmaxf(z, -15.f), 15.f);
        float e = __expf(2.f * z);            // tanh(z) = (e^2z-1)/(e^2z+1)
        float hn = (e - 1.f) * __builtin_amdgcn_rcpf(e + 1.f);
        if (q == 0) h_lds[cur ^ 1][o] = hn;   // exec-masked 4B write

        __syncthreads();                      // one barrier per step
        cur ^= 1;
    }

    // logits + log_softmax (tail, negligible)
    if (tid < OUT) {
        float a = b_fc[tid];
        const float* wf = W_fc + tid * HIDDEN;
        #pragma unroll 4
        for (int j = 0; j < HIDDEN; ++j) a += h_lds[cur][j] * wf[j];
        lg[tid] = a;
    }
    __syncthreads();
    if (tid == 0) {
        float m = fmaxf(lg[0], fmaxf(lg[1], lg[2]));
        float s = expf(lg[0] - m) + expf(lg[1] - m) + expf(lg[2] - m);
        float lse = m + logf(s);
        out[0] = lg[0] - lse;
        out[1] = lg[1] - lse;
        out[2] = lg[2] - lse;
    }
}

// ---------------------------------------------------------------------------
extern "C" void kernel_launch(void* const* d_in, const int* in_sizes, int n_in,
                              void* d_out, int out_size, void* d_ws, size_t ws_size,
                              hipStream_t stream) {
    const int*   X       = (const int*)d_in[0];
    const float* weights = (const float*)d_in[1];
    const float* W_ih    = (const float*)d_in[2];
    const float* b_ih    = (const float*)d_in[3];
    const float* W_hh    = (const float*)d_in[4];
    const float* b_hh    = (const float*)d_in[5];
    const float* W_fc    = (const float*)d_in[6];
    const float* b_fc    = (const float*)d_in[7];
    float* out   = (float*)d_out;
    float* xproj = (float*)d_ws;   // SEQ*HIDDEN*4 = 2 MB of scratch

    xproj_kernel<<<SEQ / SPB, 128, 0, stream>>>(X, weights, W_ih, b_ih, xproj);
    rnn_scan_kernel<<<1, 512, 0, stream>>>(xproj, W_hh, b_hh, W_fc, b_fc, out);
}